// Round 2
// baseline (430.048 us; speedup 1.0000x reference)
//
#include <hip/hip_runtime.h>

// Problem constants (fixed by setup_inputs)
#define BB 2
#define TT 2048
#define CC 1024
#define HH 16
#define DD 64
#define KDIM 1024
#define MROWS (BB*TT)   // 4096

typedef __attribute__((ext_vector_type(8))) short  frag_b16;  // 8 bf16 (4 VGPRs)
typedef __attribute__((ext_vector_type(4))) float  f32x4;
typedef __attribute__((ext_vector_type(4))) unsigned short us4;
typedef __attribute__((ext_vector_type(8))) unsigned short us8;
typedef __attribute__((ext_vector_type(4))) _Float16 f16x4;

__device__ __forceinline__ unsigned short f2bf(float f) {
    unsigned int u = __builtin_bit_cast(unsigned int, f);
    u += 0x7FFFu + ((u >> 16) & 1u);   // RNE
    return (unsigned short)(u >> 16);
}

// ---------------------------------------------------------------- fp32 -> bf16
__global__ __launch_bounds__(256) void cvt4(const float* __restrict__ src,
                                            unsigned short* __restrict__ dst, int n) {
    int i = (blockIdx.x * 256 + threadIdx.x) * 4;
    if (i >= n) return;
    float4 f = *reinterpret_cast<const float4*>(src + i);
    us4 o;
    o.x = f2bf(f.x); o.y = f2bf(f.y); o.z = f2bf(f.z); o.w = f2bf(f.w);
    *reinterpret_cast<us4*>(dst + i) = o;
}

// ------------------------------------------------- QKV projection (+RoPE) GEMM
__global__ __launch_bounds__(256) void qkv_gemm_rope(
        const unsigned short* __restrict__ X,
        const unsigned short* __restrict__ Wq,
        const unsigned short* __restrict__ Wk,
        const unsigned short* __restrict__ Wv,
        const float* __restrict__ bq, const float* __restrict__ bk,
        const float* __restrict__ bv,
        unsigned short* __restrict__ Qo,   // [B,H,T,D] bf16 (roped)
        unsigned short* __restrict__ Ko,   // [B,H,T,D] bf16 (roped)
        _Float16* __restrict__ VTo)        // [B,H,D,T] fp16
{
    const int z = blockIdx.z;
    const unsigned short* W = (z == 0) ? Wq : (z == 1) ? Wk : Wv;
    const float* bias = (z == 0) ? bq : (z == 1) ? bk : bv;

    const int wave = threadIdx.x >> 6;
    const int lane = threadIdx.x & 63;
    const int l16 = lane & 15;
    const int quad = lane >> 4;

    const int row0 = blockIdx.x * 128 + (wave >> 1) * 64;
    const int col0 = blockIdx.y * 128 + (wave & 1) * 64;

    f32x4 acc[4][4] = {};

    for (int kk = 0; kk < KDIM; kk += 32) {
        frag_b16 a[4], b[4];
#pragma unroll
        for (int r = 0; r < 4; ++r)
            a[r] = *reinterpret_cast<const frag_b16*>(
                X + (size_t)(row0 + r * 16 + l16) * KDIM + kk + quad * 8);
#pragma unroll
        for (int c = 0; c < 4; ++c)
            b[c] = *reinterpret_cast<const frag_b16*>(
                W + (size_t)(col0 + c * 16 + l16) * KDIM + kk + quad * 8);
#pragma unroll
        for (int r = 0; r < 4; ++r)
#pragma unroll
            for (int c = 0; c < 4; ++c)
                acc[r][c] = __builtin_amdgcn_mfma_f32_16x16x32_bf16(a[r], b[c], acc[r][c], 0, 0, 0);
    }

#pragma unroll
    for (int r = 0; r < 4; ++r) {
#pragma unroll
        for (int c = 0; c < 4; ++c) {
#pragma unroll
            for (int g = 0; g < 4; ++g) {
                int n = row0 + r * 16 + quad * 4 + g;
                int o = col0 + c * 16 + l16;
                float v = acc[r][c][g] + bias[o];
                int b_ = n >> 11;          // /T
                int t  = n & (TT - 1);
                int h  = o >> 6;
                int d  = o & (DD - 1);
                if (z == 2) {
                    VTo[(((size_t)(b_ * HH + h) * DD + d) * TT) + t] = (_Float16)v;
                } else {
                    float pv = __shfl_xor(v, 1);
                    float inv = __expf(-(float)(d & ~1) * (9.210340371976184f / (float)DD));
                    float ang = (float)t * inv;
                    float cs = cosf(ang);
                    float sn = sinf(ang);
                    float outv = (d & 1) ? (pv * sn + v * cs) : (v * cs - pv * sn);
                    unsigned short* dst = (z == 0) ? Qo : Ko;
                    dst[((size_t)(b_ * HH + h) * TT + t) * DD + d] = f2bf(outv);
                }
            }
        }
    }
}

// ------------------------------------------------------------ flash attention
// Transposed-score design: S^T = K·Q^T via 16x16x32_bf16 (A=K, B=Q), so
// q = lane&15 and keys live in registers -> row stats need only an in-reg
// reduction + 2 shuffles (xor16/xor32). Then Y^T = V^T·P^T via
// 16x16x16_f16: the P^T B-fragment (B[k=quad*4+j][n=l16]) IS the S^T
// C-layout registers -> no LDS round trip, no barriers in the K-loop.
// 4 waves/block, 32 q-rows/wave, 64 keys/iter, per-wave causal trip count.
__global__ __launch_bounds__(256, 2) void attn(
        const unsigned short* __restrict__ Q,
        const unsigned short* __restrict__ K,
        const _Float16* __restrict__ VT,
        unsigned short* __restrict__ Y)   // [B*T, C] bf16
{
    const int qblk = (int)(gridDim.x - 1 - blockIdx.x);   // heavy-first (LPT)
    const int bh = blockIdx.y;
    const int w = threadIdx.x >> 6;
    const int lane = threadIdx.x & 63;
    const int l16 = lane & 15;
    const int quad = lane >> 4;

    const int q0 = qblk * 128 + w * 32;

    const unsigned short* Qp = Q + (size_t)bh * TT * DD;
    const unsigned short* Kp = K + (size_t)bh * TT * DD;
    const _Float16* Vp = VT + (size_t)bh * DD * TT;

    __shared__ __align__(16) unsigned short Ylds[4][32][72];

    // Q fragments (B-operand of S^T): B[k=d=quad*8+j][n=q=l16]
    frag_b16 bq[2][2];
#pragma unroll
    for (int nt = 0; nt < 2; ++nt)
#pragma unroll
        for (int dk = 0; dk < 2; ++dk)
            bq[nt][dk] = *reinterpret_cast<const frag_b16*>(
                Qp + (size_t)(q0 + nt * 16 + l16) * DD + dk * 32 + quad * 8);

    f32x4 yacc[2][4] = {};   // Y^T[d=dt*16+quad*4+g][q=nt*16+l16]
    float m[2], l[2];
#pragma unroll
    for (int nt = 0; nt < 2; ++nt) { m[nt] = -INFINITY; l[nt] = 0.f; }

    const int keys_end = q0 + 32;   // exclusive causal bound for this wave
    for (int j0 = 0; j0 < keys_end; j0 += 64) {
        // K fragments (A-operand): A[m=key=l16][k=d=quad*8+j]
        frag_b16 ak[4][2];
#pragma unroll
        for (int mt = 0; mt < 4; ++mt)
#pragma unroll
            for (int dk = 0; dk < 2; ++dk)
                ak[mt][dk] = *reinterpret_cast<const frag_b16*>(
                    Kp + (size_t)(j0 + mt * 16 + l16) * DD + dk * 32 + quad * 8);

        // V^T fragments (A-operand of PV): A[m=d=l16][k=key=quad*4+j]
        f16x4 av[4][4];
#pragma unroll
        for (int dt = 0; dt < 4; ++dt)
#pragma unroll
            for (int kt = 0; kt < 4; ++kt)
                av[dt][kt] = *reinterpret_cast<const f16x4*>(
                    Vp + (size_t)(dt * 16 + l16) * TT + j0 + kt * 16 + quad * 4);

        // S^T[key][q]
        f32x4 s[4][2] = {};
#pragma unroll
        for (int mt = 0; mt < 4; ++mt)
#pragma unroll
            for (int nt = 0; nt < 2; ++nt) {
                s[mt][nt] = __builtin_amdgcn_mfma_f32_16x16x32_bf16(ak[mt][0], bq[nt][0], s[mt][nt], 0, 0, 0);
                s[mt][nt] = __builtin_amdgcn_mfma_f32_16x16x32_bf16(ak[mt][1], bq[nt][1], s[mt][nt], 0, 0, 0);
            }

        // scale + causal mask + new row max (q = nt*16+l16, key in regs)
        float nm[2] = { -INFINITY, -INFINITY };
#pragma unroll
        for (int mt = 0; mt < 4; ++mt)
#pragma unroll
            for (int nt = 0; nt < 2; ++nt)
#pragma unroll
                for (int g = 0; g < 4; ++g) {
                    int key = j0 + mt * 16 + quad * 4 + g;
                    int q   = q0 + nt * 16 + l16;
                    float v = s[mt][nt][g] * 0.125f;
                    if (key > q) v = -1e30f;
                    s[mt][nt][g] = v;
                    nm[nt] = fmaxf(nm[nt], v);
                }
#pragma unroll
        for (int nt = 0; nt < 2; ++nt) {
            nm[nt] = fmaxf(nm[nt], __shfl_xor(nm[nt], 16));
            nm[nt] = fmaxf(nm[nt], __shfl_xor(nm[nt], 32));
        }

        float alpha[2];
#pragma unroll
        for (int nt = 0; nt < 2; ++nt) {
            float mn = fmaxf(m[nt], nm[nt]);
            alpha[nt] = __expf(m[nt] - mn);
            m[nt] = mn;
        }

        // exp in place + row sum
        float rs[2] = { 0.f, 0.f };
#pragma unroll
        for (int mt = 0; mt < 4; ++mt)
#pragma unroll
            for (int nt = 0; nt < 2; ++nt)
#pragma unroll
                for (int g = 0; g < 4; ++g) {
                    float e = __expf(s[mt][nt][g] - m[nt]);
                    s[mt][nt][g] = e;
                    rs[nt] += e;
                }
#pragma unroll
        for (int nt = 0; nt < 2; ++nt) {
            rs[nt] += __shfl_xor(rs[nt], 16);
            rs[nt] += __shfl_xor(rs[nt], 32);
            l[nt] = l[nt] * alpha[nt] + rs[nt];
        }

        // pack P^T to fp16 B-fragments: B[k=key=quad*4+j][n=q=l16]
        f16x4 pb[4][2];
#pragma unroll
        for (int kt = 0; kt < 4; ++kt)
#pragma unroll
            for (int nt = 0; nt < 2; ++nt)
#pragma unroll
                for (int g = 0; g < 4; ++g)
                    pb[kt][nt][g] = (_Float16)s[kt][nt][g];

        // rescale + accumulate Y^T
#pragma unroll
        for (int nt = 0; nt < 2; ++nt)
#pragma unroll
            for (int dt = 0; dt < 4; ++dt) {
                f32x4 ya = yacc[nt][dt];
#pragma unroll
                for (int g = 0; g < 4; ++g) ya[g] *= alpha[nt];
#pragma unroll
                for (int kt = 0; kt < 4; ++kt)
                    ya = __builtin_amdgcn_mfma_f32_16x16x16f16(av[dt][kt], pb[kt][nt], ya, 0, 0, 0);
                yacc[nt][dt] = ya;
            }
    }

    // epilogue: normalize, LDS transpose (per-wave buffer), coalesced stores
    float rl[2];
#pragma unroll
    for (int nt = 0; nt < 2; ++nt) rl[nt] = 1.f / l[nt];

#pragma unroll
    for (int nt = 0; nt < 2; ++nt)
#pragma unroll
        for (int dt = 0; dt < 4; ++dt)
#pragma unroll
            for (int g = 0; g < 4; ++g)
                Ylds[w][nt * 16 + l16][dt * 16 + quad * 4 + g] =
                    f2bf(yacc[nt][dt][g] * rl[nt]);

    __syncthreads();

    const int b_ = bh >> 4, h = bh & (HH - 1);
    const int tl = lane >> 3;          // 0..7: token within group of 8
    const int c8 = (lane & 7) * 8;     // 16B column chunk
#pragma unroll
    for (int i = 0; i < 4; ++i) {
        int tok = i * 8 + tl;
        us8 v = *reinterpret_cast<const us8*>(&Ylds[w][tok][c8]);
        *reinterpret_cast<us8*>(
            &Y[(size_t)(b_ * TT + q0 + tok) * CC + h * DD + c8]) = v;
    }
}

// --------------------------------------------------------- output projection
__global__ __launch_bounds__(256) void out_gemm(
        const unsigned short* __restrict__ Y,
        const unsigned short* __restrict__ Wo,
        const float* __restrict__ bo,
        float* __restrict__ out)
{
    const int wave = threadIdx.x >> 6;
    const int lane = threadIdx.x & 63;
    const int l16 = lane & 15;
    const int quad = lane >> 4;

    const int row0 = blockIdx.x * 128 + (wave >> 1) * 64;
    const int col0 = blockIdx.y * 128 + (wave & 1) * 64;

    f32x4 acc[4][4] = {};

    for (int kk = 0; kk < KDIM; kk += 32) {
        frag_b16 a[4], b[4];
#pragma unroll
        for (int r = 0; r < 4; ++r)
            a[r] = *reinterpret_cast<const frag_b16*>(
                Y + (size_t)(row0 + r * 16 + l16) * KDIM + kk + quad * 8);
#pragma unroll
        for (int c = 0; c < 4; ++c)
            b[c] = *reinterpret_cast<const frag_b16*>(
                Wo + (size_t)(col0 + c * 16 + l16) * KDIM + kk + quad * 8);
#pragma unroll
        for (int r = 0; r < 4; ++r)
#pragma unroll
            for (int c = 0; c < 4; ++c)
                acc[r][c] = __builtin_amdgcn_mfma_f32_16x16x32_bf16(a[r], b[c], acc[r][c], 0, 0, 0);
    }

#pragma unroll
    for (int r = 0; r < 4; ++r)
#pragma unroll
        for (int c = 0; c < 4; ++c)
#pragma unroll
            for (int g = 0; g < 4; ++g) {
                int n = row0 + r * 16 + quad * 4 + g;
                int o = col0 + c * 16 + l16;
                out[(size_t)n * CC + o] = acc[r][c][g] + bo[o];
            }
}

// ---------------------------------------------------------------------- launch
extern "C" void kernel_launch(void* const* d_in, const int* in_sizes, int n_in,
                              void* d_out, int out_size, void* d_ws, size_t ws_size,
                              hipStream_t stream) {
    const float* x  = (const float*)d_in[0];
    const float* Wq = (const float*)d_in[1];
    const float* bq = (const float*)d_in[2];
    const float* Wk = (const float*)d_in[3];
    const float* bk = (const float*)d_in[4];
    const float* Wv = (const float*)d_in[5];
    const float* bv = (const float*)d_in[6];
    const float* Wo = (const float*)d_in[7];
    const float* bo = (const float*)d_in[8];
    float* out = (float*)d_out;

    unsigned short* ws = (unsigned short*)d_ws;
    const size_t NX = (size_t)MROWS * CC;      // 4194304
    const size_t NW = (size_t)CC * CC;         // 1048576
    unsigned short* xb  = ws;
    unsigned short* wqb = xb  + NX;
    unsigned short* wkb = wqb + NW;
    unsigned short* wvb = wkb + NW;
    unsigned short* wob = wvb + NW;
    unsigned short* Qr  = wob + NW;
    unsigned short* Kr  = Qr  + NX;
    _Float16*       VTb = (_Float16*)(Kr + NX);
    unsigned short* Yb  = (unsigned short*)(VTb + NX);

    cvt4<<<dim3((unsigned)(NX / 1024)), 256, 0, stream>>>(x,  xb,  (int)NX);
    cvt4<<<dim3((unsigned)(NW / 1024)), 256, 0, stream>>>(Wq, wqb, (int)NW);
    cvt4<<<dim3((unsigned)(NW / 1024)), 256, 0, stream>>>(Wk, wkb, (int)NW);
    cvt4<<<dim3((unsigned)(NW / 1024)), 256, 0, stream>>>(Wv, wvb, (int)NW);
    cvt4<<<dim3((unsigned)(NW / 1024)), 256, 0, stream>>>(Wo, wob, (int)NW);

    qkv_gemm_rope<<<dim3(MROWS / 128, CC / 128, 3), 256, 0, stream>>>(
        xb, wqb, wkb, wvb, bq, bk, bv, Qr, Kr, VTb);

    attn<<<dim3(TT / 128, BB * HH), 256, 0, stream>>>(Qr, Kr, VTb, Yb);

    out_gemm<<<dim3(MROWS / 128, CC / 128), 256, 0, stream>>>(Yb, wob, bo, out);
}